// Round 2
// baseline (15847.981 us; speedup 1.0000x reference)
//
#include <hip/hip_runtime.h>
#include <cmath>

#define U_N 128
#define H_N 512
#define V_N 2048
#define S_LEN 512
#define HU (U_N * H_N)   // 65536 floats per GRU timestep state

// log2(e)
#define LOG2E 1.4426950408889634f
// exp(-dt/DAY * 0.1) = exp2(dt * LT_C)
#define LT_C (-0.1f / 86400.0f * LOG2E)
// exp(-1.0 * dist) = exp2(dist * LS_C)
#define LS_C (-LOG2E)

// ---------------------------------------------------------------------------
// Generic f32 GEMM: C[M,N] = A[M,K] @ B[N,K]^T + bias[N]
// Tiles 128x128, 256 threads, micro 8x8, BK=8, K-major LDS.
// Requires M%128==0, N%128==0, K%8==0.
// ---------------------------------------------------------------------------
__global__ __launch_bounds__(256) void gemm_abt_f32(
    const float* __restrict__ A, const float* __restrict__ B,
    const float* __restrict__ bias, float* __restrict__ C,
    int N, int K)
{
  __shared__ float As[8][132];
  __shared__ float Bs[8][132];
  const int m0 = blockIdx.x * 128, n0 = blockIdx.y * 128;
  const int tid = threadIdx.x;
  const int tx = tid & 15, ty = tid >> 4;
  const int lrow = tid >> 1, lk = (tid & 1) * 4;
  const float* Ap = A + (size_t)(m0 + lrow) * K + lk;
  const float* Bp = B + (size_t)(n0 + lrow) * K + lk;
  float acc[8][8] = {};
  for (int k0 = 0; k0 < K; k0 += 8) {
    float4 av = *(const float4*)(Ap + k0);
    float4 bv = *(const float4*)(Bp + k0);
    __syncthreads();
    As[lk+0][lrow] = av.x; As[lk+1][lrow] = av.y;
    As[lk+2][lrow] = av.z; As[lk+3][lrow] = av.w;
    Bs[lk+0][lrow] = bv.x; Bs[lk+1][lrow] = bv.y;
    Bs[lk+2][lrow] = bv.z; Bs[lk+3][lrow] = bv.w;
    __syncthreads();
#pragma unroll
    for (int k = 0; k < 8; k++) {
      float a[8], b[8];
      *(float4*)&a[0] = *(const float4*)&As[k][ty*8];
      *(float4*)&a[4] = *(const float4*)&As[k][ty*8+4];
      *(float4*)&b[0] = *(const float4*)&Bs[k][tx*8];
      *(float4*)&b[4] = *(const float4*)&Bs[k][tx*8+4];
#pragma unroll
      for (int i = 0; i < 8; i++)
#pragma unroll
        for (int j = 0; j < 8; j++)
          acc[i][j] += a[i] * b[j];
    }
  }
  float bb[8];
#pragma unroll
  for (int j = 0; j < 8; j++) bb[j] = bias[n0 + tx*8 + j];
#pragma unroll
  for (int i = 0; i < 8; i++) {
    float* crow = C + (size_t)(m0 + ty*8 + i) * N + n0 + tx*8;
    float4 v0 = make_float4(acc[i][0]+bb[0], acc[i][1]+bb[1],
                            acc[i][2]+bb[2], acc[i][3]+bb[3]);
    float4 v1 = make_float4(acc[i][4]+bb[4], acc[i][5]+bb[5],
                            acc[i][6]+bb[6], acc[i][7]+bb[7]);
    *(float4*)crow = v0;
    *(float4*)(crow + 4) = v1;
  }
}

// ---------------------------------------------------------------------------
// One GRU timestep.
// grid (8 u-tiles of 16, 16 d-tiles of 32); block 256.
// Computes gh = h_prev @ W_hh^T for 3 gate-rows of its 32 dims, then gates.
// gi comes from the pre-folded C1 = emb @ W_ih^T + b_ih, gathered by x.
// ---------------------------------------------------------------------------
__global__ __launch_bounds__(256) void gru_step(
    const float* __restrict__ hprev,  // [128][512]
    const float* __restrict__ Whh,    // [1536][512]
    const float* __restrict__ bhh,    // [1536]
    const float* __restrict__ C1,     // [2048][1536]
    const int*   __restrict__ xrow,   // [128]
    float* __restrict__ hout)         // [128][512]
{
  __shared__ float hs[16][129];   // h chunk, +1 pad: conflict-free b32 reads
  __shared__ float ws[96][129];   // 3 gates x 32 dims rows
  const int u0 = blockIdx.x * 16;
  const int d0 = blockIdx.y * 32;
  const int tid = threadIdx.x;
  const int dl = tid & 31;        // dim within tile
  const int uu = tid >> 5;        // user pair 0..7
  float acc[3][2] = {};
  for (int k0 = 0; k0 < 512; k0 += 128) {
    for (int idx = tid; idx < 16*32; idx += 256) {
      int r = idx >> 5, c4 = (idx & 31) * 4;
      float4 v = *(const float4*)(hprev + (size_t)(u0 + r)*512 + k0 + c4);
      hs[r][c4+0] = v.x; hs[r][c4+1] = v.y; hs[r][c4+2] = v.z; hs[r][c4+3] = v.w;
    }
    for (int idx = tid; idx < 96*32; idx += 256) {
      int r = idx >> 5, c4 = (idx & 31) * 4;
      int g = r >> 5, dd = r & 31;
      float4 v = *(const float4*)(Whh + (size_t)(g*512 + d0 + dd)*512 + k0 + c4);
      ws[r][c4+0] = v.x; ws[r][c4+1] = v.y; ws[r][c4+2] = v.z; ws[r][c4+3] = v.w;
    }
    __syncthreads();
#pragma unroll 8
    for (int k = 0; k < 128; k++) {
      float h0v = hs[uu*2+0][k];
      float h1v = hs[uu*2+1][k];
      float w0 = ws[dl][k], w1 = ws[32+dl][k], w2 = ws[64+dl][k];
      acc[0][0] += h0v*w0; acc[0][1] += h1v*w0;
      acc[1][0] += h0v*w1; acc[1][1] += h1v*w1;
      acc[2][0] += h0v*w2; acc[2][1] += h1v*w2;
    }
    __syncthreads();
  }
  const int d = d0 + dl;
  const float br = bhh[d], bz = bhh[512 + d], bn = bhh[1024 + d];
#pragma unroll
  for (int i = 0; i < 2; i++) {
    int u = u0 + uu*2 + i;
    int xv = xrow[u];
    const float* c1 = C1 + (size_t)xv * 1536;
    float r = 1.0f / (1.0f + expf(-(c1[d]       + acc[0][i] + br)));
    float z = 1.0f / (1.0f + expf(-(c1[512 + d] + acc[1][i] + bz)));
    float hn = acc[2][i] + bn;
    float n = tanhf(c1[1024 + d] + r * hn);
    hout[(size_t)u*512 + d] = (1.0f - z) * n + z * hprev[(size_t)u*512 + d];
  }
}

// ---------------------------------------------------------------------------
// Causal spatiotemporal weighting, per user:
// out_w[i,u,:] = sum_{j<=i} w(i,j,u) * out[j,u,:] / sum_j w(i,j,u)
// grid (8 i-tiles of 64, 8 h-tiles of 64, 128 users); block 256, micro 4x4.
// ---------------------------------------------------------------------------
__global__ __launch_bounds__(256) void stweight(
    const float* __restrict__ T,    // [512][128]
    const float* __restrict__ Sp,   // [512][128][2]
    const float* __restrict__ out,  // [512][128][512]
    float* __restrict__ outw)       // [512][128][512]
{
  __shared__ float Ws[16][68];
  __shared__ float Os[16][68];
  __shared__ float tis[64], sxs[64], sys[64];
  __shared__ float swp[4][64];
  __shared__ float swrow[64];
  const int i0 = blockIdx.x * 64;
  const int h0 = blockIdx.y * 64;
  const int u  = blockIdx.z;
  const int tid = threadIdx.x;
  if (tid < 64) {
    int gi = i0 + tid;
    tis[tid] = T[(size_t)gi*128 + u];
    sxs[tid] = Sp[((size_t)gi*128 + u)*2 + 0];
    sys[tid] = Sp[((size_t)gi*128 + u)*2 + 1];
  }
  __syncthreads();
  const int il = tid & 63, jg = tid >> 6;   // materialization mapping
  const float ti = tis[il], sxi = sxs[il], syi = sys[il];
  const int gi = i0 + il;
  float swsum = 0.0f;
  const int tx = tid & 15, ty = tid >> 4;
  float acc[4][4] = {};
  const int nch = (i0 >> 4) + 4;            // chunks of 16 j, j <= i0+63
  for (int c = 0; c < nch; c++) {
    int j0 = c * 16;
    {
      int jl = tid >> 4, cc = (tid & 15) * 4;
      float4 ov = *(const float4*)(out + ((size_t)(j0 + jl)*128 + u)*512 + h0 + cc);
      *(float4*)&Os[jl][cc] = ov;
    }
#pragma unroll
    for (int jj = 0; jj < 4; jj++) {
      int j = j0 + jg*4 + jj;
      float w = 0.0f;
      if (j <= gi) {
        float tj  = T[(size_t)j*128 + u];
        float sxj = Sp[((size_t)j*128 + u)*2 + 0];
        float syj = Sp[((size_t)j*128 + u)*2 + 1];
        float dt = ti - tj;
        float dx = sxi - sxj, dy = syi - syj;
        float dist = sqrtf(dx*dx + dy*dy);
        w = exp2f(dt * LT_C) * exp2f(dist * LS_C) + 1e-10f;
      }
      Ws[jg*4 + jj][il] = w;
      swsum += w;
    }
    __syncthreads();
#pragma unroll
    for (int k = 0; k < 16; k++) {
      float a[4], b[4];
      *(float4*)&a[0] = *(const float4*)&Ws[k][ty*4];
      *(float4*)&b[0] = *(const float4*)&Os[k][tx*4];
#pragma unroll
      for (int i = 0; i < 4; i++)
#pragma unroll
        for (int j = 0; j < 4; j++)
          acc[i][j] += a[i] * b[j];
    }
    __syncthreads();
  }
  swp[jg][il] = swsum;
  __syncthreads();
  if (tid < 64) swrow[tid] = swp[0][tid] + swp[1][tid] + swp[2][tid] + swp[3][tid];
  __syncthreads();
#pragma unroll
  for (int i = 0; i < 4; i++) {
    int girow = i0 + ty*4 + i;
    float inv = 1.0f / swrow[ty*4 + i];
    float4 v = make_float4(acc[i][0]*inv, acc[i][1]*inv, acc[i][2]*inv, acc[i][3]*inv);
    *(float4*)(outw + ((size_t)girow*128 + u)*512 + h0 + tx*4) = v;
  }
}

// ---------------------------------------------------------------------------
__global__ __launch_bounds__(256) void copy_hlast(
    const float* __restrict__ src, float* __restrict__ dst)
{
  int i = blockIdx.x * 256 + threadIdx.x;   // 16384 float4s
  ((float4*)dst)[i] = ((const float4*)src)[i];
}

// ---------------------------------------------------------------------------
extern "C" void kernel_launch(void* const* d_in, const int* in_sizes, int n_in,
                              void* d_out, int out_size, void* d_ws, size_t ws_size,
                              hipStream_t stream)
{
  const int*   x    = (const int*)  d_in[0];
  const float* t    = (const float*)d_in[1];
  const float* sp   = (const float*)d_in[2];
  const float* h0   = (const float*)d_in[5];
  const float* emb  = (const float*)d_in[7];
  const float* Wih  = (const float*)d_in[8];
  const float* Whh  = (const float*)d_in[9];
  const float* bih  = (const float*)d_in[10];
  const float* bhh  = (const float*)d_in[11];
  const float* fcw  = (const float*)d_in[12];
  const float* fcb  = (const float*)d_in[13];

  float* y = (float*)d_out;                         // [512][128][2048]
  float* hlast = y + (size_t)S_LEN * U_N * V_N;     // [128][512]

  float* wsf  = (float*)d_ws;
  float* C1   = wsf;                                // 2048*1536
  float* out  = C1 + (size_t)V_N * 1536;            // 512*128*512
  float* outw = out + (size_t)S_LEN * HU;           // 512*128*512

  // 1. C1 = emb @ W_ih^T + b_ih   [2048 x 1536], K=512
  gemm_abt_f32<<<dim3(V_N/128, 1536/128), 256, 0, stream>>>(emb, Wih, bih, C1, 1536, 512);

  // 2. GRU recurrence, one kernel per step
  for (int s = 0; s < S_LEN; s++) {
    const float* hp = (s == 0) ? h0 : (out + (size_t)(s - 1) * HU);
    gru_step<<<dim3(8, 16), 256, 0, stream>>>(hp, Whh, bhh, C1, x + s * U_N,
                                              out + (size_t)s * HU);
  }

  // 3. causal spatiotemporal weighting
  stweight<<<dim3(8, 8, U_N), 256, 0, stream>>>(t, sp, out, outw);

  // 4. y = out_w @ fc_w^T + fc_b   [65536 x 2048], K=512
  gemm_abt_f32<<<dim3((S_LEN*U_N)/128, V_N/128), 256, 0, stream>>>(outw, fcw, fcb, y, V_N, 512);

  // 5. h_last
  copy_hlast<<<64, 256, 0, stream>>>(out + (size_t)(S_LEN - 1) * HU, hlast);
}